// Round 10
// baseline (103.363 us; speedup 1.0000x reference)
//
#include <hip/hip_runtime.h>
#include <hip/hip_bf16.h>

#define NEG_SLOPE 0.01f
#define NPB 512          // nodes per coarse bucket (dst >> 9)
#define CHUNK 4096       // edges per block in partition pass

typedef __attribute__((ext_vector_type(8))) short short8;
typedef __attribute__((ext_vector_type(4))) float f32x4;

__device__ __forceinline__ unsigned short f2bf_rne(float f) {
    unsigned u = __float_as_uint(f);
    u += 0x7FFFu + ((u >> 16) & 1u);       // round-to-nearest-even
    return (unsigned short)(u >> 16);
}

// Fused K1: blocks [0, G1) = MFMA GEMM (z = h @ W1^T, bf16 out);
// blocks [G1, G1+G2) = edge partition pass. Disjoint data -> safe overlap.
// GEMM: 256 rows/block; wave = 64 rows as 4 row-groups of 16, pipelined.
__global__ __launch_bounds__(256, 4) void k_gp(
    const float* __restrict__ h, const float* __restrict__ W1,
    unsigned short* __restrict__ zb, int N, int G1,
    const int* __restrict__ src, const int* __restrict__ dst,
    unsigned* __restrict__ gcur, unsigned* __restrict__ table,
    int E, int NBKT, int BCAP)
{
    __shared__ __align__(16) union SM {
        struct { short wsb[64 * 128]; short tbuf[4][16 * 64]; } g;       // 24 KB
        struct {
            unsigned cnt[256]; unsigned exc[256]; unsigned sbuf[256];
            unsigned gbaseb[256]; unsigned stage[CHUNK];
            unsigned short bkt[CHUNK];
        } p;                                                             // 28 KB
    } sm;
    const int tid = threadIdx.x;

    if (blockIdx.x < (unsigned)G1) {
        // ---------------- GEMM path ----------------
        const int nb = blockIdx.x * 256;
        const int w  = tid >> 6;
        const int l  = tid & 63;
        const int lr = l & 15;
        const int lc = l >> 4;
        const int rowbase = nb + w * 64;
        const float4* __restrict__ h4 = (const float4*)h;
        const float4* __restrict__ W14 = (const float4*)W1;

        // Prologue: row-group 0's A loads (8 x 16B, independent).
        float4 av[8];
        {
            const int myn = rowbase + lr;
#pragma unroll
            for (int ks = 0; ks < 4; ++ks) {
                const int kcb = ks * 4 + lc;
                if (myn < N) {
                    av[2 * ks]     = h4[(size_t)myn * 32 + kcb * 2];
                    av[2 * ks + 1] = h4[(size_t)myn * 32 + kcb * 2 + 1];
                } else {
                    av[2 * ks]     = make_float4(0.f, 0.f, 0.f, 0.f);
                    av[2 * ks + 1] = make_float4(0.f, 0.f, 0.f, 0.f);
                }
            }
        }

        // Stage W1 (64x128) into LDS bf16, XOR-swizzled for b128 reads.
#pragma unroll
        for (int it = 0; it < 4; ++it) {
            const int q = tid + it * 256;
            const int r = q >> 4, cb = q & 15;
            float4 v0 = W14[(size_t)r * 32 + cb * 2];
            float4 v1 = W14[(size_t)r * 32 + cb * 2 + 1];
            short8 o;
            o[0]=f2bf_rne(v0.x); o[1]=f2bf_rne(v0.y); o[2]=f2bf_rne(v0.z); o[3]=f2bf_rne(v0.w);
            o[4]=f2bf_rne(v1.x); o[5]=f2bf_rne(v1.y); o[6]=f2bf_rne(v1.z); o[7]=f2bf_rne(v1.w);
            *(short8*)&sm.g.wsb[r * 128 + ((cb * 8) ^ ((r & 7) << 3))] = o;
        }
        __syncthreads();

        short* __restrict__ tb = sm.g.tbuf[w];      // per-wave, no barriers

#pragma unroll
        for (int rg = 0; rg < 4; ++rg) {
            short8 afr[4];
#pragma unroll
            for (int ks = 0; ks < 4; ++ks) {
                const float4 v0 = av[2 * ks], v1 = av[2 * ks + 1];
                short8 o;
                o[0]=f2bf_rne(v0.x); o[1]=f2bf_rne(v0.y); o[2]=f2bf_rne(v0.z); o[3]=f2bf_rne(v0.w);
                o[4]=f2bf_rne(v1.x); o[5]=f2bf_rne(v1.y); o[6]=f2bf_rne(v1.z); o[7]=f2bf_rne(v1.w);
                afr[ks] = o;
            }
            if (rg < 3) {
                const int myn = rowbase + (rg + 1) * 16 + lr;
#pragma unroll
                for (int ks = 0; ks < 4; ++ks) {
                    const int kcb = ks * 4 + lc;
                    if (myn < N) {
                        av[2 * ks]     = h4[(size_t)myn * 32 + kcb * 2];
                        av[2 * ks + 1] = h4[(size_t)myn * 32 + kcb * 2 + 1];
                    } else {
                        av[2 * ks]     = make_float4(0.f, 0.f, 0.f, 0.f);
                        av[2 * ks + 1] = make_float4(0.f, 0.f, 0.f, 0.f);
                    }
                }
            }

            f32x4 acc[4];
#pragma unroll
            for (int ni = 0; ni < 4; ++ni) acc[ni] = (f32x4){0.f, 0.f, 0.f, 0.f};
#pragma unroll
            for (int ks = 0; ks < 4; ++ks) {
                const int kcb = ks * 4 + lc;
#pragma unroll
                for (int ni = 0; ni < 4; ++ni) {
                    const int wr = ni * 16 + lr;
                    const short8 bf = *(const short8*)&sm.g.wsb[wr * 128 + ((kcb * 8) ^ ((wr & 7) << 3))];
                    acc[ni] = __builtin_amdgcn_mfma_f32_16x16x32_bf16(afr[ks], bf, acc[ni], 0, 0, 0);
                }
            }

            // z transpose through per-wave LDS -> coalesced 16B stores.
            // C/D: col = lane&15 (=lr), row = (lane>>4)*4 + reg.
#pragma unroll
            for (int ni = 0; ni < 4; ++ni) {
                const int col = ni * 16 + lr;
#pragma unroll
                for (int r = 0; r < 4; ++r) {
                    const int ro = lc * 4 + r;
                    tb[ro * 64 + (((col >> 3) ^ (ro & 7)) << 3) + (col & 7)]
                        = (short)f2bf_rne(acc[ni][r]);
                }
            }
            {
                const int ro = l >> 2;
                const int n = rowbase + rg * 16 + ro;
                if (n < N) {
#pragma unroll
                    for (int j = 0; j < 2; ++j) {
                        const int c = (l & 3) * 2 + j;
                        const short8 v = *(const short8*)&tb[ro * 64 + ((c ^ (ro & 7)) << 3)];
                        *(short8*)&zb[(size_t)n * 64 + c * 8] = v;
                    }
                }
            }
        }
    } else {
        // ---------------- Partition path ----------------
        const int e0 = (blockIdx.x - G1) * CHUNK;
        const int nE = min(CHUNK, E - e0);

        sm.p.cnt[tid] = 0u;
        __syncthreads();
        for (int i = tid; i < nE; i += 256)
            atomicAdd(&sm.p.cnt[(unsigned)dst[e0 + i] >> 9], 1u);
        __syncthreads();

        const unsigned myc = sm.p.cnt[tid];
        if (tid < NBKT && myc > 0u) sm.p.gbaseb[tid] = atomicAdd(&gcur[tid], myc);

        sm.p.sbuf[tid] = myc;
        __syncthreads();
        for (int off = 1; off < 256; off <<= 1) {
            unsigned x = (tid >= off) ? sm.p.sbuf[tid - off] : 0u;
            __syncthreads();
            sm.p.sbuf[tid] += x;
            __syncthreads();
        }
        sm.p.exc[tid] = sm.p.sbuf[tid] - myc;
        __syncthreads();
        sm.p.cnt[tid] = 0u;
        __syncthreads();

        for (int i = tid; i < nE; i += 256) {
            const unsigned d = (unsigned)dst[e0 + i];
            const unsigned b = d >> 9;
            const unsigned pos = sm.p.exc[b] + atomicAdd(&sm.p.cnt[b], 1u);
            sm.p.stage[pos] = ((unsigned)src[e0 + i] << 9) | (d & 511u);
            sm.p.bkt[pos] = (unsigned short)b;
        }
        __syncthreads();

        for (int i = tid; i < nE; i += 256) {
            const unsigned b = sm.p.bkt[i];
            const unsigned off = sm.p.gbaseb[b] + ((unsigned)i - sm.p.exc[b]);
            if (off < (unsigned)BCAP)
                table[(size_t)b * BCAP + off] = sm.p.stage[i];
        }
    }
}

// Pass B: one block per coarse bucket; recomputes the global bucket-base
// prefix itself, then LDS count/scan/scatter.
__global__ __launch_bounds__(256) void k_sortb2(
    const unsigned* __restrict__ table, const unsigned* __restrict__ gcur,
    unsigned* __restrict__ edge_src,
    unsigned* __restrict__ offsets, unsigned* __restrict__ counts,
    int N, int NBKT, int BCAP)
{
    __shared__ unsigned ncnt[NPB];
    __shared__ unsigned nexc[NPB];
    __shared__ unsigned sbuf[NPB];
    __shared__ unsigned basesh;
    const int b = blockIdx.x;
    const int t = threadIdx.x;
    const int bc = min((int)gcur[b], BCAP);
    const size_t tb = (size_t)b * BCAP;

    {
        unsigned c = (t < NBKT) ? min(gcur[t], (unsigned)BCAP) : 0u;
        sbuf[t] = c;
        __syncthreads();
        for (int off = 1; off < 256; off <<= 1) {
            unsigned x = (t >= off) ? sbuf[t - off] : 0u;
            __syncthreads();
            sbuf[t] += x;
            __syncthreads();
        }
        if (t == 0) basesh = (b == 0) ? 0u : sbuf[b - 1];
        __syncthreads();
    }
    const unsigned base = basesh;
    __syncthreads();

    ncnt[t] = 0u; ncnt[t + 256] = 0u;
    __syncthreads();
    for (int i = t; i < bc; i += 256)
        atomicAdd(&ncnt[table[tb + i] & 511u], 1u);
    __syncthreads();

    const unsigned c0 = ncnt[t], c1 = ncnt[t + 256];
    sbuf[t] = c0; sbuf[t + 256] = c1;
    __syncthreads();
    for (int off = 1; off < NPB; off <<= 1) {
        unsigned x0 = (t >= off) ? sbuf[t - off] : 0u;
        unsigned x1 = (t + 256 >= off) ? sbuf[t + 256 - off] : 0u;
        __syncthreads();
        sbuf[t] += x0; sbuf[t + 256] += x1;
        __syncthreads();
    }
    nexc[t] = sbuf[t] - c0; nexc[t + 256] = sbuf[t + 256] - c1;
    __syncthreads();

    {
        const int n0 = b * NPB + t, n1 = n0 + 256;
        if (n0 < N) { offsets[n0] = base + nexc[t];        counts[n0] = c0; }
        if (n1 < N) { offsets[n1] = base + nexc[t + 256];  counts[n1] = c1; }
    }
    ncnt[t] = 0u; ncnt[t + 256] = 0u;
    __syncthreads();

    for (int i = t; i < bc; i += 256) {
        const unsigned v = table[tb + i];
        const unsigned l = v & 511u;
        const unsigned pos = nexc[l] + atomicAdd(&ncnt[l], 1u);
        edge_src[base + pos] = v >> 9;
    }
}

// Fused per-dst softmax + aggregate, logits computed FROM the gathered z:
// e_j = z[sj].a_src + z[node].a_dst. 16 lanes/node (2 edge-halves x 8 dim-
// lanes); all 8 gathers of a half batched into vv[8] (32 VGPRs in flight).
__global__ __launch_bounds__(256) void k_node(
    const unsigned* __restrict__ offsets, const unsigned* __restrict__ counts,
    const unsigned* __restrict__ edge_src, const float* __restrict__ Wa,
    const unsigned short* __restrict__ zb, float* __restrict__ out, int N)
{
    const int tid = threadIdx.x;
    const int node = blockIdx.x * 16 + (tid >> 4);
    if (node >= N) return;
    const int wl    = tid & 63;
    const int gbase = wl & ~15;
    const int sub   = wl & 15;
    const int g2    = sub >> 3;        // edge half (0/1)
    const int l8    = sub & 7;         // dim slice: dims l8*8..l8*8+7

    const unsigned beg = offsets[node];
    const int cnt = (int)counts[node];
    if (cnt == 0) {
        if (sub < 8) {
            const float4 zz = make_float4(0.f, 0.f, 0.f, 0.f);
            *(float4*)&out[(size_t)node * 64 + sub * 8]     = zz;
            *(float4*)&out[(size_t)node * 64 + sub * 8 + 4] = zz;
        }
        return;
    }

    // a_src slice (my 8 dims)
    const float4 as0 = *(const float4*)&Wa[l8 * 8];
    const float4 as1 = *(const float4*)&Wa[l8 * 8 + 4];

    // t_node = z[node] . a_dst ; lane covers dims sub*4..sub*4+3
    float tn;
    {
        const uint2 zn = *(const uint2*)&zb[(size_t)node * 64 + sub * 4];
        const float4 ad = *(const float4*)&Wa[64 + sub * 4];
        float pd = __uint_as_float(zn.x << 16) * ad.x
                 + __uint_as_float(zn.x & 0xFFFF0000u) * ad.y
                 + __uint_as_float(zn.y << 16) * ad.z
                 + __uint_as_float(zn.y & 0xFFFF0000u) * ad.w;
#pragma unroll
        for (int m = 1; m < 16; m <<= 1) pd += __shfl_xor(pd, m);
        tn = pd;
    }

    float dl = 0.f;
    float acc[8] = {0.f, 0.f, 0.f, 0.f, 0.f, 0.f, 0.f, 0.f};

    for (int base = 0; base < cnt; base += 16) {
        const int rem = cnt - base;          // may exceed 16 (clamped by use)
        int sj = 0;
        if (sub < rem) sj = (int)edge_src[beg + base + sub];

        // Batch-issue all 8 gathers of my half (independent 16B loads).
        uint4 vv[8];
#pragma unroll
        for (int k = 0; k < 8; ++k) {
            const int sjj = __shfl(sj, gbase + g2 * 8 + k);
            vv[k] = *(const uint4*)&zb[(size_t)sjj * 64 + l8 * 8];
        }
#pragma unroll
        for (int k = 0; k < 8; ++k) {
            const uint4 v = vv[k];
            const float z0 = __uint_as_float(v.x << 16);
            const float z1 = __uint_as_float(v.x & 0xFFFF0000u);
            const float z2 = __uint_as_float(v.y << 16);
            const float z3 = __uint_as_float(v.y & 0xFFFF0000u);
            const float z4 = __uint_as_float(v.z << 16);
            const float z5 = __uint_as_float(v.z & 0xFFFF0000u);
            const float z6 = __uint_as_float(v.w << 16);
            const float z7 = __uint_as_float(v.w & 0xFFFF0000u);
            float pd = z0 * as0.x;
            pd = fmaf(z1, as0.y, pd); pd = fmaf(z2, as0.z, pd);
            pd = fmaf(z3, as0.w, pd); pd = fmaf(z4, as1.x, pd);
            pd = fmaf(z5, as1.y, pd); pd = fmaf(z6, as1.z, pd);
            pd = fmaf(z7, as1.w, pd);
            pd += __shfl_xor(pd, 1);
            pd += __shfl_xor(pd, 2);
            pd += __shfl_xor(pd, 4);
            float e = pd + tn;
            e = (e >= 0.f) ? e : NEG_SLOPE * e;
            const float p = ((g2 << 3) + k < rem) ? __expf(e) : 0.f;
            dl += p;
            acc[0] = fmaf(p, z0, acc[0]); acc[1] = fmaf(p, z1, acc[1]);
            acc[2] = fmaf(p, z2, acc[2]); acc[3] = fmaf(p, z3, acc[3]);
            acc[4] = fmaf(p, z4, acc[4]); acc[5] = fmaf(p, z5, acc[5]);
            acc[6] = fmaf(p, z6, acc[6]); acc[7] = fmaf(p, z7, acc[7]);
        }
    }

#pragma unroll
    for (int c = 0; c < 8; ++c)                 // combine the 2 edge halves
        acc[c] += __shfl_xor(acc[c], 8);
    const float den = dl + __shfl_xor(dl, 8);

    if (sub < 8) {
        const float inv = 1.f / fmaxf(den, 1e-16f);
        float4 o0 = make_float4(acc[0] * inv, acc[1] * inv, acc[2] * inv, acc[3] * inv);
        float4 o1 = make_float4(acc[4] * inv, acc[5] * inv, acc[6] * inv, acc[7] * inv);
        *(float4*)&out[(size_t)node * 64 + sub * 8]     = o0;
        *(float4*)&out[(size_t)node * 64 + sub * 8 + 4] = o1;
    }
}

extern "C" void kernel_launch(void* const* d_in, const int* in_sizes, int n_in,
                              void* d_out, int out_size, void* d_ws, size_t ws_size,
                              hipStream_t stream) {
    const float* h   = (const float*)d_in[0];
    const int*   src = (const int*)d_in[1];
    const int*   dst = (const int*)d_in[2];
    const float* W1  = (const float*)d_in[3];
    const float* Wa  = (const float*)d_in[4];
    float* out = (float*)d_out;

    const int N = in_sizes[0] / 128;
    const int E = in_sizes[1];
    const int NBKT = (N + NPB - 1) / NPB;            // <=256
    const int meanb = (E + NBKT - 1) / NBKT;
    int slack = 24 * (int)sqrtf((float)meanb) + 64;  // mean + 24 sigma
    const int BCAP = meanb + slack;

    const int G1 = (N + 255) / 256;                  // gemm blocks (256 rows each)
    const int G2 = (E + CHUNK - 1) / CHUNK;          // partition blocks

    // ws: zb(N*64 bf16) | gcur | offsets | counts | edge_src(E) | table(NBKT*BCAP)
    unsigned short* zb = (unsigned short*)d_ws;
    unsigned* gcur     = (unsigned*)(zb + (size_t)N * 64);
    unsigned* offsets  = gcur + NBKT;
    unsigned* counts   = offsets + N;
    unsigned* edge_src = counts + N;
    unsigned* table    = edge_src + E;

    hipMemsetAsync(gcur, 0, (size_t)NBKT * sizeof(unsigned), stream);

    k_gp<<<G1 + G2, 256, 0, stream>>>(h, W1, zb, N, G1,
                                      src, dst, gcur, table, E, NBKT, BCAP);
    k_sortb2<<<NBKT, 256, 0, stream>>>(table, gcur, edge_src, offsets, counts, N, NBKT, BCAP);
    k_node<<<(N + 15) / 16, 256, 0, stream>>>(offsets, counts, edge_src, Wa, zb, out, N);
}

// Round 11
// 99.724 us; speedup vs baseline: 1.0365x; 1.0365x over previous
//
#include <hip/hip_runtime.h>
#include <hip/hip_bf16.h>

#define NEG_SLOPE 0.01f
#define NPB 512          // nodes per coarse bucket (dst >> 9)
#define CHUNK 4096       // edges per block in partition pass

typedef __attribute__((ext_vector_type(8))) short short8;
typedef __attribute__((ext_vector_type(4))) float f32x4;

__device__ __forceinline__ unsigned short f2bf_rne(float f) {
    unsigned u = __float_as_uint(f);
    u += 0x7FFFu + ((u >> 16) & 1u);       // round-to-nearest-even
    return (unsigned short)(u >> 16);
}

// Fused K1: blocks [0, G1) = MFMA GEMM (z = h @ W1^T, bf16 out);
// blocks [G1, G1+G2) = edge partition pass. Disjoint data -> safe overlap.
__global__ __launch_bounds__(256, 4) void k_gp(
    const float* __restrict__ h, const float* __restrict__ W1,
    unsigned short* __restrict__ zb, int N, int G1,
    const int* __restrict__ src, const int* __restrict__ dst,
    unsigned* __restrict__ gcur, unsigned* __restrict__ table,
    int E, int NBKT, int BCAP)
{
    __shared__ __align__(16) union SM {
        struct { short wsb[64 * 128]; short tbuf[4][16 * 64]; } g;       // 24 KB
        struct {
            unsigned cnt[256]; unsigned exc[256]; unsigned sbuf[256];
            unsigned gbaseb[256]; unsigned stage[CHUNK];
            unsigned short bkt[CHUNK];
        } p;                                                             // 28 KB
    } sm;
    const int tid = threadIdx.x;

    if (blockIdx.x < (unsigned)G1) {
        // ---------------- GEMM path ----------------
        const int nb = blockIdx.x * 256;
        const int w  = tid >> 6;
        const int l  = tid & 63;
        const int lr = l & 15;
        const int lc = l >> 4;
        const int rowbase = nb + w * 64;
        const float4* __restrict__ h4 = (const float4*)h;
        const float4* __restrict__ W14 = (const float4*)W1;

        float4 av[8];
        {
            const int myn = rowbase + lr;
#pragma unroll
            for (int ks = 0; ks < 4; ++ks) {
                const int kcb = ks * 4 + lc;
                if (myn < N) {
                    av[2 * ks]     = h4[(size_t)myn * 32 + kcb * 2];
                    av[2 * ks + 1] = h4[(size_t)myn * 32 + kcb * 2 + 1];
                } else {
                    av[2 * ks]     = make_float4(0.f, 0.f, 0.f, 0.f);
                    av[2 * ks + 1] = make_float4(0.f, 0.f, 0.f, 0.f);
                }
            }
        }

#pragma unroll
        for (int it = 0; it < 4; ++it) {
            const int q = tid + it * 256;
            const int r = q >> 4, cb = q & 15;
            float4 v0 = W14[(size_t)r * 32 + cb * 2];
            float4 v1 = W14[(size_t)r * 32 + cb * 2 + 1];
            short8 o;
            o[0]=f2bf_rne(v0.x); o[1]=f2bf_rne(v0.y); o[2]=f2bf_rne(v0.z); o[3]=f2bf_rne(v0.w);
            o[4]=f2bf_rne(v1.x); o[5]=f2bf_rne(v1.y); o[6]=f2bf_rne(v1.z); o[7]=f2bf_rne(v1.w);
            *(short8*)&sm.g.wsb[r * 128 + ((cb * 8) ^ ((r & 7) << 3))] = o;
        }
        __syncthreads();

        short* __restrict__ tb = sm.g.tbuf[w];      // per-wave, no barriers

#pragma unroll
        for (int rg = 0; rg < 4; ++rg) {
            short8 afr[4];
#pragma unroll
            for (int ks = 0; ks < 4; ++ks) {
                const float4 v0 = av[2 * ks], v1 = av[2 * ks + 1];
                short8 o;
                o[0]=f2bf_rne(v0.x); o[1]=f2bf_rne(v0.y); o[2]=f2bf_rne(v0.z); o[3]=f2bf_rne(v0.w);
                o[4]=f2bf_rne(v1.x); o[5]=f2bf_rne(v1.y); o[6]=f2bf_rne(v1.z); o[7]=f2bf_rne(v1.w);
                afr[ks] = o;
            }
            if (rg < 3) {
                const int myn = rowbase + (rg + 1) * 16 + lr;
#pragma unroll
                for (int ks = 0; ks < 4; ++ks) {
                    const int kcb = ks * 4 + lc;
                    if (myn < N) {
                        av[2 * ks]     = h4[(size_t)myn * 32 + kcb * 2];
                        av[2 * ks + 1] = h4[(size_t)myn * 32 + kcb * 2 + 1];
                    } else {
                        av[2 * ks]     = make_float4(0.f, 0.f, 0.f, 0.f);
                        av[2 * ks + 1] = make_float4(0.f, 0.f, 0.f, 0.f);
                    }
                }
            }

            f32x4 acc[4];
#pragma unroll
            for (int ni = 0; ni < 4; ++ni) acc[ni] = (f32x4){0.f, 0.f, 0.f, 0.f};
#pragma unroll
            for (int ks = 0; ks < 4; ++ks) {
                const int kcb = ks * 4 + lc;
#pragma unroll
                for (int ni = 0; ni < 4; ++ni) {
                    const int wr = ni * 16 + lr;
                    const short8 bf = *(const short8*)&sm.g.wsb[wr * 128 + ((kcb * 8) ^ ((wr & 7) << 3))];
                    acc[ni] = __builtin_amdgcn_mfma_f32_16x16x32_bf16(afr[ks], bf, acc[ni], 0, 0, 0);
                }
            }

            // z transpose via per-wave LDS -> coalesced 16B stores.
#pragma unroll
            for (int ni = 0; ni < 4; ++ni) {
                const int col = ni * 16 + lr;
#pragma unroll
                for (int r = 0; r < 4; ++r) {
                    const int ro = lc * 4 + r;
                    tb[ro * 64 + (((col >> 3) ^ (ro & 7)) << 3) + (col & 7)]
                        = (short)f2bf_rne(acc[ni][r]);
                }
            }
            {
                const int ro = l >> 2;
                const int n = rowbase + rg * 16 + ro;
                if (n < N) {
#pragma unroll
                    for (int j = 0; j < 2; ++j) {
                        const int c = (l & 3) * 2 + j;
                        const short8 v = *(const short8*)&tb[ro * 64 + ((c ^ (ro & 7)) << 3)];
                        *(short8*)&zb[(size_t)n * 64 + c * 8] = v;
                    }
                }
            }
        }
    } else {
        // ---------------- Partition path ----------------
        const int e0 = (blockIdx.x - G1) * CHUNK;
        const int nE = min(CHUNK, E - e0);

        sm.p.cnt[tid] = 0u;
        __syncthreads();
        for (int i = tid; i < nE; i += 256)
            atomicAdd(&sm.p.cnt[(unsigned)dst[e0 + i] >> 9], 1u);
        __syncthreads();

        const unsigned myc = sm.p.cnt[tid];
        if (tid < NBKT && myc > 0u) sm.p.gbaseb[tid] = atomicAdd(&gcur[tid], myc);

        sm.p.sbuf[tid] = myc;
        __syncthreads();
        for (int off = 1; off < 256; off <<= 1) {
            unsigned x = (tid >= off) ? sm.p.sbuf[tid - off] : 0u;
            __syncthreads();
            sm.p.sbuf[tid] += x;
            __syncthreads();
        }
        sm.p.exc[tid] = sm.p.sbuf[tid] - myc;
        __syncthreads();
        sm.p.cnt[tid] = 0u;
        __syncthreads();

        for (int i = tid; i < nE; i += 256) {
            const unsigned d = (unsigned)dst[e0 + i];
            const unsigned b = d >> 9;
            const unsigned pos = sm.p.exc[b] + atomicAdd(&sm.p.cnt[b], 1u);
            sm.p.stage[pos] = ((unsigned)src[e0 + i] << 9) | (d & 511u);
            sm.p.bkt[pos] = (unsigned short)b;
        }
        __syncthreads();

        for (int i = tid; i < nE; i += 256) {
            const unsigned b = sm.p.bkt[i];
            const unsigned off = sm.p.gbaseb[b] + ((unsigned)i - sm.p.exc[b]);
            if (off < (unsigned)BCAP)
                table[(size_t)b * BCAP + off] = sm.p.stage[i];
        }
    }
}

// Fused pass B: blocks [0, NBKT) = per-bucket CSR sort (recomputes global
// prefix locally); blocks [NBKT, NBKT+GST) = s/t = zb . a_src / a_dst
// (coalesced, 8 lanes/node). Disjoint outputs -> safe in one kernel.
__global__ __launch_bounds__(256) void k_sp(
    const unsigned* __restrict__ table, const unsigned* __restrict__ gcur,
    unsigned* __restrict__ edge_src,
    unsigned* __restrict__ offsets, unsigned* __restrict__ counts,
    const unsigned short* __restrict__ zb, const float* __restrict__ Wa,
    float* __restrict__ s, float* __restrict__ t,
    int N, int NBKT, int BCAP)
{
    __shared__ unsigned ncnt[NPB];
    __shared__ unsigned nexc[NPB];
    __shared__ unsigned sbuf[NPB];
    __shared__ unsigned basesh;
    const int tid = threadIdx.x;

    if (blockIdx.x >= (unsigned)NBKT) {
        // ---------------- s/t path ----------------
        const int node = ((int)blockIdx.x - NBKT) * 32 + (tid >> 3);
        const int l8 = tid & 7;
        if (node < N) {
            const uint4 v = *(const uint4*)&zb[(size_t)node * 64 + l8 * 8];
            const float4 a0 = *(const float4*)&Wa[l8 * 8];
            const float4 a1 = *(const float4*)&Wa[l8 * 8 + 4];
            const float4 d0 = *(const float4*)&Wa[64 + l8 * 8];
            const float4 d1 = *(const float4*)&Wa[64 + l8 * 8 + 4];
            const float z0 = __uint_as_float(v.x << 16);
            const float z1 = __uint_as_float(v.x & 0xFFFF0000u);
            const float z2 = __uint_as_float(v.y << 16);
            const float z3 = __uint_as_float(v.y & 0xFFFF0000u);
            const float z4 = __uint_as_float(v.z << 16);
            const float z5 = __uint_as_float(v.z & 0xFFFF0000u);
            const float z6 = __uint_as_float(v.w << 16);
            const float z7 = __uint_as_float(v.w & 0xFFFF0000u);
            float ps = z0 * a0.x;
            ps = fmaf(z1, a0.y, ps); ps = fmaf(z2, a0.z, ps); ps = fmaf(z3, a0.w, ps);
            ps = fmaf(z4, a1.x, ps); ps = fmaf(z5, a1.y, ps); ps = fmaf(z6, a1.z, ps);
            ps = fmaf(z7, a1.w, ps);
            float pt = z0 * d0.x;
            pt = fmaf(z1, d0.y, pt); pt = fmaf(z2, d0.z, pt); pt = fmaf(z3, d0.w, pt);
            pt = fmaf(z4, d1.x, pt); pt = fmaf(z5, d1.y, pt); pt = fmaf(z6, d1.z, pt);
            pt = fmaf(z7, d1.w, pt);
#pragma unroll
            for (int m = 1; m < 8; m <<= 1) {
                ps += __shfl_xor(ps, m);
                pt += __shfl_xor(pt, m);
            }
            if (l8 == 0) { s[node] = ps; t[node] = pt; }
        }
        return;
    }

    // ---------------- sort path ----------------
    const int b = blockIdx.x;
    const int bc = min((int)gcur[b], BCAP);
    const size_t tb = (size_t)b * BCAP;

    {
        unsigned c = (tid < NBKT) ? min(gcur[tid], (unsigned)BCAP) : 0u;
        sbuf[tid] = c;
        __syncthreads();
        for (int off = 1; off < 256; off <<= 1) {
            unsigned x = (tid >= off) ? sbuf[tid - off] : 0u;
            __syncthreads();
            sbuf[tid] += x;
            __syncthreads();
        }
        if (tid == 0) basesh = (b == 0) ? 0u : sbuf[b - 1];
        __syncthreads();
    }
    const unsigned base = basesh;
    __syncthreads();

    ncnt[tid] = 0u; ncnt[tid + 256] = 0u;
    __syncthreads();
    for (int i = tid; i < bc; i += 256)
        atomicAdd(&ncnt[table[tb + i] & 511u], 1u);
    __syncthreads();

    const unsigned c0 = ncnt[tid], c1 = ncnt[tid + 256];
    sbuf[tid] = c0; sbuf[tid + 256] = c1;
    __syncthreads();
    for (int off = 1; off < NPB; off <<= 1) {
        unsigned x0 = (tid >= off) ? sbuf[tid - off] : 0u;
        unsigned x1 = (tid + 256 >= off) ? sbuf[tid + 256 - off] : 0u;
        __syncthreads();
        sbuf[tid] += x0; sbuf[tid + 256] += x1;
        __syncthreads();
    }
    nexc[tid] = sbuf[tid] - c0; nexc[tid + 256] = sbuf[tid + 256] - c1;
    __syncthreads();

    {
        const int n0 = b * NPB + tid, n1 = n0 + 256;
        if (n0 < N) { offsets[n0] = base + nexc[tid];        counts[n0] = c0; }
        if (n1 < N) { offsets[n1] = base + nexc[tid + 256];  counts[n1] = c1; }
    }
    ncnt[tid] = 0u; ncnt[tid + 256] = 0u;
    __syncthreads();

    for (int i = tid; i < bc; i += 256) {
        const unsigned v = table[tb + i];
        const unsigned l = v & 511u;
        const unsigned pos = nexc[l] + atomicAdd(&ncnt[l], 1u);
        edge_src[base + pos] = v >> 9;
    }
}

// Fused per-dst softmax + aggregate. 16 lanes/node, 4 nodes/wave.
// Logits: lane = edge (s[sj] gather, 400KB L2-resident). Aggregate: 2 edge-
// halves x 8 dim-lanes with BATCHED vv[8] gathers (32 VGPRs in flight).
__global__ __launch_bounds__(256) void k_node(
    const unsigned* __restrict__ offsets, const unsigned* __restrict__ counts,
    const unsigned* __restrict__ edge_src,
    const float* __restrict__ s, const float* __restrict__ t,
    const unsigned short* __restrict__ zb, float* __restrict__ out, int N)
{
    const int tid = threadIdx.x;
    const int node = blockIdx.x * 16 + (tid >> 4);
    if (node >= N) return;
    const int wl    = tid & 63;
    const int gbase = wl & ~15;
    const int sub   = wl & 15;
    const int g2    = sub >> 3;        // edge half (0/1)
    const int l8    = sub & 7;         // dim slice

    const unsigned beg = offsets[node];
    const int cnt = (int)counts[node];
    if (cnt == 0) {
        if (sub < 8) {
            const float4 zz = make_float4(0.f, 0.f, 0.f, 0.f);
            *(float4*)&out[(size_t)node * 64 + sub * 8]     = zz;
            *(float4*)&out[(size_t)node * 64 + sub * 8 + 4] = zz;
        }
        return;
    }

    const float tn = t[node];
    const unsigned short* __restrict__ zrow = zb + l8 * 8;
    float dl = 0.f;
    float acc[8] = {0.f, 0.f, 0.f, 0.f, 0.f, 0.f, 0.f, 0.f};

    for (int base = 0; base < cnt; base += 16) {
        const int rem = cnt - base;
        int sj = 0;
        float p = 0.f;
        if (sub < rem) {
            sj = (int)edge_src[beg + base + sub];
            float e = s[sj] + tn;
            e = (e >= 0.f) ? e : NEG_SLOPE * e;
            p = __expf(e);
            dl += p;
        }
        // Batch-issue my half's 8 gathers (independent 16B loads).
        uint4 vv[8];
#pragma unroll
        for (int k = 0; k < 8; ++k) {
            const int sjj = __shfl(sj, gbase + g2 * 8 + k);
            vv[k] = *(const uint4*)&zrow[(size_t)sjj * 64];
        }
#pragma unroll
        for (int k = 0; k < 8; ++k) {
            const float pj = __shfl(p, gbase + g2 * 8 + k);
            const uint4 v = vv[k];
#define UNPK(u, d0) \
            acc[d0]     = fmaf(pj, __uint_as_float((u) << 16),          acc[d0]); \
            acc[d0 + 1] = fmaf(pj, __uint_as_float((u) & 0xFFFF0000u), acc[d0 + 1]);
            UNPK(v.x, 0) UNPK(v.y, 2) UNPK(v.z, 4) UNPK(v.w, 6)
#undef UNPK
        }
    }

#pragma unroll
    for (int c = 0; c < 8; ++c)                 // combine the 2 edge halves
        acc[c] += __shfl_xor(acc[c], 8);
    float den = dl;
#pragma unroll
    for (int m = 1; m < 16; m <<= 1) den += __shfl_xor(den, m);

    if (sub < 8) {
        const float inv = 1.f / fmaxf(den, 1e-16f);
        float4 o0 = make_float4(acc[0] * inv, acc[1] * inv, acc[2] * inv, acc[3] * inv);
        float4 o1 = make_float4(acc[4] * inv, acc[5] * inv, acc[6] * inv, acc[7] * inv);
        *(float4*)&out[(size_t)node * 64 + sub * 8]     = o0;
        *(float4*)&out[(size_t)node * 64 + sub * 8 + 4] = o1;
    }
}

extern "C" void kernel_launch(void* const* d_in, const int* in_sizes, int n_in,
                              void* d_out, int out_size, void* d_ws, size_t ws_size,
                              hipStream_t stream) {
    const float* h   = (const float*)d_in[0];
    const int*   src = (const int*)d_in[1];
    const int*   dst = (const int*)d_in[2];
    const float* W1  = (const float*)d_in[3];
    const float* Wa  = (const float*)d_in[4];
    float* out = (float*)d_out;

    const int N = in_sizes[0] / 128;
    const int E = in_sizes[1];
    const int NBKT = (N + NPB - 1) / NPB;            // <=256
    const int meanb = (E + NBKT - 1) / NBKT;
    int slack = 24 * (int)sqrtf((float)meanb) + 64;  // mean + 24 sigma
    const int BCAP = meanb + slack;

    const int G1 = (N + 255) / 256;                  // gemm blocks (256 rows each)
    const int G2 = (E + CHUNK - 1) / CHUNK;          // partition blocks
    const int GST = (N + 31) / 32;                   // s/t blocks

    // ws: zb(N*64 bf16) | s(N) | t(N) | gcur | offsets | counts |
    //     edge_src(E) | table(NBKT*BCAP)
    unsigned short* zb = (unsigned short*)d_ws;
    float*    s        = (float*)(zb + (size_t)N * 64);
    float*    t        = s + N;
    unsigned* gcur     = (unsigned*)(t + N);
    unsigned* offsets  = gcur + NBKT;
    unsigned* counts   = offsets + N;
    unsigned* edge_src = counts + N;
    unsigned* table    = edge_src + E;

    hipMemsetAsync(gcur, 0, (size_t)NBKT * sizeof(unsigned), stream);

    k_gp<<<G1 + G2, 256, 0, stream>>>(h, W1, zb, N, G1,
                                      src, dst, gcur, table, E, NBKT, BCAP);
    k_sp<<<NBKT + GST, 256, 0, stream>>>(table, gcur, edge_src, offsets, counts,
                                         zb, Wa, s, t, N, NBKT, BCAP);
    k_node<<<(N + 15) / 16, 256, 0, stream>>>(offsets, counts, edge_src, s, t, zb, out, N);
}

// Round 12
// 95.195 us; speedup vs baseline: 1.0858x; 1.0476x over previous
//
#include <hip/hip_runtime.h>
#include <hip/hip_bf16.h>

#define NEG_SLOPE 0.01f
#define NPB 512          // nodes per coarse bucket (dst >> 9)
#define CHUNK 4096       // edges per block in partition pass

typedef __attribute__((ext_vector_type(8))) short short8;
typedef __attribute__((ext_vector_type(4))) float f32x4;

__device__ __forceinline__ unsigned short f2bf_rne(float f) {
    unsigned u = __float_as_uint(f);
    u += 0x7FFFu + ((u >> 16) & 1u);       // round-to-nearest-even
    return (unsigned short)(u >> 16);
}

// Fused K1: blocks [0, G1) = MFMA GEMM (z = h @ W1^T bf16, + s,t from f32 acc);
// blocks [G1, G1+G2) = edge partition pass. Disjoint data -> safe overlap.
__global__ __launch_bounds__(256, 4) void k_gp(
    const float* __restrict__ h, const float* __restrict__ W1,
    const float* __restrict__ Wa, unsigned short* __restrict__ zb,
    float* __restrict__ s, float* __restrict__ t, int N, int G1,
    const int* __restrict__ src, const int* __restrict__ dst,
    unsigned* __restrict__ gcur, unsigned* __restrict__ table,
    int E, int NBKT, int BCAP)
{
    __shared__ __align__(16) union SM {
        struct { short wsb[64 * 128]; short tbuf[4][16 * 64]; } g;       // 24 KB
        struct {
            unsigned cnt[256]; unsigned exc[256]; unsigned sbuf[256];
            unsigned gbaseb[256]; unsigned stage[CHUNK];
            unsigned short bkt[CHUNK];
        } p;                                                             // 28 KB
    } sm;
    const int tid = threadIdx.x;

    if (blockIdx.x < (unsigned)G1) {
        // ---------------- GEMM path ----------------
        const int nb = blockIdx.x * 256;
        const int w  = tid >> 6;
        const int l  = tid & 63;
        const int lr = l & 15;
        const int lc = l >> 4;
        const int rowbase = nb + w * 64;
        const float4* __restrict__ h4 = (const float4*)h;
        const float4* __restrict__ W14 = (const float4*)W1;

        float asrc[4], adst[4];
#pragma unroll
        for (int ni = 0; ni < 4; ++ni) {
            asrc[ni] = Wa[ni * 16 + lr];
            adst[ni] = Wa[64 + ni * 16 + lr];
        }

        float4 av[8];
        {
            const int myn = rowbase + lr;
#pragma unroll
            for (int ks = 0; ks < 4; ++ks) {
                const int kcb = ks * 4 + lc;
                if (myn < N) {
                    av[2 * ks]     = h4[(size_t)myn * 32 + kcb * 2];
                    av[2 * ks + 1] = h4[(size_t)myn * 32 + kcb * 2 + 1];
                } else {
                    av[2 * ks]     = make_float4(0.f, 0.f, 0.f, 0.f);
                    av[2 * ks + 1] = make_float4(0.f, 0.f, 0.f, 0.f);
                }
            }
        }

#pragma unroll
        for (int it = 0; it < 4; ++it) {
            const int q = tid + it * 256;
            const int r = q >> 4, cb = q & 15;
            float4 v0 = W14[(size_t)r * 32 + cb * 2];
            float4 v1 = W14[(size_t)r * 32 + cb * 2 + 1];
            short8 o;
            o[0]=f2bf_rne(v0.x); o[1]=f2bf_rne(v0.y); o[2]=f2bf_rne(v0.z); o[3]=f2bf_rne(v0.w);
            o[4]=f2bf_rne(v1.x); o[5]=f2bf_rne(v1.y); o[6]=f2bf_rne(v1.z); o[7]=f2bf_rne(v1.w);
            *(short8*)&sm.g.wsb[r * 128 + ((cb * 8) ^ ((r & 7) << 3))] = o;
        }
        __syncthreads();

        short* __restrict__ tb = sm.g.tbuf[w];      // per-wave, no barriers

#pragma unroll
        for (int rg = 0; rg < 4; ++rg) {
            short8 afr[4];
#pragma unroll
            for (int ks = 0; ks < 4; ++ks) {
                const float4 v0 = av[2 * ks], v1 = av[2 * ks + 1];
                short8 o;
                o[0]=f2bf_rne(v0.x); o[1]=f2bf_rne(v0.y); o[2]=f2bf_rne(v0.z); o[3]=f2bf_rne(v0.w);
                o[4]=f2bf_rne(v1.x); o[5]=f2bf_rne(v1.y); o[6]=f2bf_rne(v1.z); o[7]=f2bf_rne(v1.w);
                afr[ks] = o;
            }
            if (rg < 3) {
                const int myn = rowbase + (rg + 1) * 16 + lr;
#pragma unroll
                for (int ks = 0; ks < 4; ++ks) {
                    const int kcb = ks * 4 + lc;
                    if (myn < N) {
                        av[2 * ks]     = h4[(size_t)myn * 32 + kcb * 2];
                        av[2 * ks + 1] = h4[(size_t)myn * 32 + kcb * 2 + 1];
                    } else {
                        av[2 * ks]     = make_float4(0.f, 0.f, 0.f, 0.f);
                        av[2 * ks + 1] = make_float4(0.f, 0.f, 0.f, 0.f);
                    }
                }
            }

            f32x4 acc[4];
#pragma unroll
            for (int ni = 0; ni < 4; ++ni) acc[ni] = (f32x4){0.f, 0.f, 0.f, 0.f};
#pragma unroll
            for (int ks = 0; ks < 4; ++ks) {
                const int kcb = ks * 4 + lc;
#pragma unroll
                for (int ni = 0; ni < 4; ++ni) {
                    const int wr = ni * 16 + lr;
                    const short8 bf = *(const short8*)&sm.g.wsb[wr * 128 + ((kcb * 8) ^ ((wr & 7) << 3))];
                    acc[ni] = __builtin_amdgcn_mfma_f32_16x16x32_bf16(afr[ks], bf, acc[ni], 0, 0, 0);
                }
            }

            // s,t epilogue (f32 acc). C/D: col = lr, row = lc*4 + r.
#pragma unroll
            for (int r = 0; r < 4; ++r) {
                float ps = 0.f, pt = 0.f;
#pragma unroll
                for (int ni = 0; ni < 4; ++ni) {
                    ps = fmaf(acc[ni][r], asrc[ni], ps);
                    pt = fmaf(acc[ni][r], adst[ni], pt);
                }
#pragma unroll
                for (int m = 1; m < 16; m <<= 1) {
                    ps += __shfl_xor(ps, m);
                    pt += __shfl_xor(pt, m);
                }
                const int node = rowbase + rg * 16 + lc * 4 + r;
                if (lr == 0 && node < N) { s[node] = ps; t[node] = pt; }
            }

            // z transpose via per-wave LDS -> coalesced 16B stores.
#pragma unroll
            for (int ni = 0; ni < 4; ++ni) {
                const int col = ni * 16 + lr;
#pragma unroll
                for (int r = 0; r < 4; ++r) {
                    const int ro = lc * 4 + r;
                    tb[ro * 64 + (((col >> 3) ^ (ro & 7)) << 3) + (col & 7)]
                        = (short)f2bf_rne(acc[ni][r]);
                }
            }
            {
                const int ro = l >> 2;
                const int n = rowbase + rg * 16 + ro;
                if (n < N) {
#pragma unroll
                    for (int j = 0; j < 2; ++j) {
                        const int c = (l & 3) * 2 + j;
                        const short8 v = *(const short8*)&tb[ro * 64 + ((c ^ (ro & 7)) << 3)];
                        *(short8*)&zb[(size_t)n * 64 + c * 8] = v;
                    }
                }
            }
        }
    } else {
        // ---------------- Partition path ----------------
        const int e0 = (blockIdx.x - G1) * CHUNK;
        const int nE = min(CHUNK, E - e0);

        sm.p.cnt[tid] = 0u;
        __syncthreads();
        for (int i = tid; i < nE; i += 256)
            atomicAdd(&sm.p.cnt[(unsigned)dst[e0 + i] >> 9], 1u);
        __syncthreads();

        const unsigned myc = sm.p.cnt[tid];
        if (tid < NBKT && myc > 0u) sm.p.gbaseb[tid] = atomicAdd(&gcur[tid], myc);

        sm.p.sbuf[tid] = myc;
        __syncthreads();
        for (int off = 1; off < 256; off <<= 1) {
            unsigned x = (tid >= off) ? sm.p.sbuf[tid - off] : 0u;
            __syncthreads();
            sm.p.sbuf[tid] += x;
            __syncthreads();
        }
        sm.p.exc[tid] = sm.p.sbuf[tid] - myc;
        __syncthreads();
        sm.p.cnt[tid] = 0u;
        __syncthreads();

        for (int i = tid; i < nE; i += 256) {
            const unsigned d = (unsigned)dst[e0 + i];
            const unsigned b = d >> 9;
            const unsigned pos = sm.p.exc[b] + atomicAdd(&sm.p.cnt[b], 1u);
            sm.p.stage[pos] = ((unsigned)src[e0 + i] << 9) | (d & 511u);
            sm.p.bkt[pos] = (unsigned short)b;
        }
        __syncthreads();

        for (int i = tid; i < nE; i += 256) {
            const unsigned b = sm.p.bkt[i];
            const unsigned off = sm.p.gbaseb[b] + ((unsigned)i - sm.p.exc[b]);
            if (off < (unsigned)BCAP)
                table[(size_t)b * BCAP + off] = sm.p.stage[i];
        }
    }
}

// Pass B (one block of 512 per coarse bucket): recompute global prefix,
// LDS histogram+scan over 512 nodes, then scatter WITH per-edge softmax
// numerator p = exp(leaky(s[src]+t[dst])) and LDS-atomic denominator.
// Emits edge_ps = (p, src) pairs, offsets/counts, invden.
__global__ __launch_bounds__(512) void k_sp(
    const unsigned* __restrict__ table, const unsigned* __restrict__ gcur,
    const float* __restrict__ s, const float* __restrict__ t,
    uint2* __restrict__ edge_ps, unsigned* __restrict__ offsets,
    unsigned* __restrict__ counts, float* __restrict__ invden,
    int N, int NBKT, int BCAP)
{
    __shared__ unsigned ncnt[NPB], nexc[NPB], scur[NPB], sbuf[NPB];
    __shared__ float tlds[NPB], den[NPB];
    __shared__ unsigned basesh;
    const int tid = threadIdx.x;
    const int b = blockIdx.x;
    const int bc = min((int)gcur[b], BCAP);
    const size_t tbo = (size_t)b * BCAP;
    const int node = b * NPB + tid;

    // global base prefix over bucket totals
    {
        unsigned c = (tid < NBKT) ? min(gcur[tid], (unsigned)BCAP) : 0u;
        sbuf[tid] = c;
        __syncthreads();
        for (int off = 1; off < NPB; off <<= 1) {
            unsigned x = (tid >= off) ? sbuf[tid - off] : 0u;
            __syncthreads();
            sbuf[tid] += x;
            __syncthreads();
        }
        if (tid == 0) basesh = (b == 0) ? 0u : sbuf[b - 1];
    }
    tlds[tid] = (node < N) ? t[node] : 0.f;
    den[tid] = 0.f;
    ncnt[tid] = 0u;
    __syncthreads();
    const unsigned base = basesh;

    for (int i = tid; i < bc; i += NPB)
        atomicAdd(&ncnt[table[tbo + i] & 511u], 1u);
    __syncthreads();

    const unsigned c0 = ncnt[tid];
    sbuf[tid] = c0;
    __syncthreads();
    for (int off = 1; off < NPB; off <<= 1) {
        unsigned x = (tid >= off) ? sbuf[tid - off] : 0u;
        __syncthreads();
        sbuf[tid] += x;
        __syncthreads();
    }
    nexc[tid] = sbuf[tid] - c0;
    scur[tid] = 0u;
    __syncthreads();

    if (node < N) { offsets[node] = base + nexc[tid]; counts[node] = c0; }

    for (int i = tid; i < bc; i += NPB) {
        const unsigned v = table[tbo + i];
        const unsigned l = v & 511u;
        const unsigned sj = v >> 9;
        float e = s[sj] + tlds[l];
        e = (e >= 0.f) ? e : NEG_SLOPE * e;
        const float p = __expf(e);
        const unsigned pos = nexc[l] + atomicAdd(&scur[l], 1u);
        edge_ps[base + pos] = make_uint2(__float_as_uint(p), sj);
        atomicAdd(&den[l], p);
    }
    __syncthreads();
    if (node < N) invden[node] = 1.f / fmaxf(den[tid], 1e-16f);
}

// Pure gather-accumulate: out[node] = invden * sum p_j * z[src_j].
// 16 lanes/node, 4 nodes/wave; 2 edge-halves x 8 dim-lanes; batched vv[8].
__global__ __launch_bounds__(256) void k_node(
    const unsigned* __restrict__ offsets, const unsigned* __restrict__ counts,
    const uint2* __restrict__ edge_ps, const float* __restrict__ invden,
    const unsigned short* __restrict__ zb, float* __restrict__ out, int N)
{
    const int tid = threadIdx.x;
    const int node = blockIdx.x * 16 + (tid >> 4);
    if (node >= N) return;
    const int wl    = tid & 63;
    const int gbase = wl & ~15;
    const int sub   = wl & 15;
    const int g2    = sub >> 3;        // edge half (0/1)
    const int l8    = sub & 7;         // dim slice

    const unsigned beg = offsets[node];
    const int cnt = (int)counts[node];
    if (cnt == 0) {
        if (sub < 8) {
            const float4 zz = make_float4(0.f, 0.f, 0.f, 0.f);
            *(float4*)&out[(size_t)node * 64 + sub * 8]     = zz;
            *(float4*)&out[(size_t)node * 64 + sub * 8 + 4] = zz;
        }
        return;
    }

    const float invd = invden[node];
    const unsigned short* __restrict__ zrow = zb + l8 * 8;
    float acc[8] = {0.f, 0.f, 0.f, 0.f, 0.f, 0.f, 0.f, 0.f};

    for (int base = 0; base < cnt; base += 16) {
        const int rem = cnt - base;
        uint2 ep = make_uint2(0u, 0u);          // p=0, sj=0 for inactive slots
        if (sub < rem) ep = edge_ps[beg + base + sub];
        const float p = __uint_as_float(ep.x);
        const int  sj = (int)ep.y;

        uint4 vv[8];
#pragma unroll
        for (int k = 0; k < 8; ++k) {
            const int sjj = __shfl(sj, gbase + g2 * 8 + k);
            vv[k] = *(const uint4*)&zrow[(size_t)sjj * 64];
        }
#pragma unroll
        for (int k = 0; k < 8; ++k) {
            const float pj = __shfl(p, gbase + g2 * 8 + k);
            const uint4 v = vv[k];
#define UNPK(u, d0) \
            acc[d0]     = fmaf(pj, __uint_as_float((u) << 16),          acc[d0]); \
            acc[d0 + 1] = fmaf(pj, __uint_as_float((u) & 0xFFFF0000u), acc[d0 + 1]);
            UNPK(v.x, 0) UNPK(v.y, 2) UNPK(v.z, 4) UNPK(v.w, 6)
#undef UNPK
        }
    }

#pragma unroll
    for (int c = 0; c < 8; ++c)                 // combine the 2 edge halves
        acc[c] += __shfl_xor(acc[c], 8);

    if (sub < 8) {
        float4 o0 = make_float4(acc[0] * invd, acc[1] * invd, acc[2] * invd, acc[3] * invd);
        float4 o1 = make_float4(acc[4] * invd, acc[5] * invd, acc[6] * invd, acc[7] * invd);
        *(float4*)&out[(size_t)node * 64 + sub * 8]     = o0;
        *(float4*)&out[(size_t)node * 64 + sub * 8 + 4] = o1;
    }
}

extern "C" void kernel_launch(void* const* d_in, const int* in_sizes, int n_in,
                              void* d_out, int out_size, void* d_ws, size_t ws_size,
                              hipStream_t stream) {
    const float* h   = (const float*)d_in[0];
    const int*   src = (const int*)d_in[1];
    const int*   dst = (const int*)d_in[2];
    const float* W1  = (const float*)d_in[3];
    const float* Wa  = (const float*)d_in[4];
    float* out = (float*)d_out;

    const int N = in_sizes[0] / 128;
    const int E = in_sizes[1];
    const int NBKT = (N + NPB - 1) / NPB;            // <=256
    const int meanb = (E + NBKT - 1) / NBKT;
    int slack = 24 * (int)sqrtf((float)meanb) + 64;  // mean + 24 sigma
    const int BCAP = meanb + slack;

    const int G1 = (N + 255) / 256;                  // gemm blocks (256 rows each)
    const int G2 = (E + CHUNK - 1) / CHUNK;          // partition blocks

    // ws: zb(N*64 bf16) | s(N) | t(N) | gcur(NBKT) | offsets(N) | counts(N) |
    //     invden(N) | edge_ps(E u64) | table(NBKT*BCAP)
    unsigned short* zb = (unsigned short*)d_ws;
    float*    s        = (float*)(zb + (size_t)N * 64);
    float*    t        = s + N;
    unsigned* gcur     = (unsigned*)(t + N);
    unsigned* offsets  = gcur + NBKT;
    unsigned* counts   = offsets + N;
    float*    invden   = (float*)(counts + N);
    uint2*    edge_ps  = (uint2*)(invden + N);
    unsigned* table    = (unsigned*)(edge_ps + E);

    hipMemsetAsync(gcur, 0, (size_t)NBKT * sizeof(unsigned), stream);

    k_gp<<<G1 + G2, 256, 0, stream>>>(h, W1, Wa, zb, s, t, N, G1,
                                      src, dst, gcur, table, E, NBKT, BCAP);
    k_sp<<<NBKT, 512, 0, stream>>>(table, gcur, s, t, edge_ps, offsets, counts,
                                   invden, N, NBKT, BCAP);
    k_node<<<(N + 15) / 16, 256, 0, stream>>>(offsets, counts, edge_ps, invden, zb, out, N);
}